// Round 1
// baseline (7567.652 us; speedup 1.0000x reference)
//
#include <hip/hip_runtime.h>
#include <cmath>

#define REGP 0.1f
#define NIT 200
#define K2 (1.4426950408889634f / REGP)   // log2(e)/reg

typedef float  vf4  __attribute__((ext_vector_type(4)));
typedef short  vbf8 __attribute__((ext_vector_type(8)));   // 8 x bf16 bits
typedef unsigned short vu8 __attribute__((ext_vector_type(8)));
typedef _Float16 vh8 __attribute__((ext_vector_type(8)));

static __device__ __forceinline__ unsigned short f2bf(float x) {
    unsigned int u = __float_as_uint(x);
    return (unsigned short)((u + 0x7FFFu + ((u >> 16) & 1u)) >> 16);
}

static __device__ __forceinline__ float wave_red_sum(float v) {
    #pragma unroll
    for (int o = 32; o > 0; o >>= 1) v += __shfl_xor(v, o, 64);
    return v;
}

// online logsumexp update for 8 elements: t_e = g_e - c_e
static __device__ __forceinline__ void upd(vh8 h, vf4 ga, vf4 gb, float& m, float& s) {
    float t0 = ga[0] - (float)h[0], t1 = ga[1] - (float)h[1];
    float t2 = ga[2] - (float)h[2], t3 = ga[3] - (float)h[3];
    float t4 = gb[0] - (float)h[4], t5 = gb[1] - (float)h[5];
    float t6 = gb[2] - (float)h[6], t7 = gb[3] - (float)h[7];
    float mc = fmaxf(fmaxf(fmaxf(t0, t1), fmaxf(t2, t3)),
                     fmaxf(fmaxf(t4, t5), fmaxf(t6, t7)));
    float mn = fmaxf(m, mc);
    float a  = exp2f((t0 - mn) * K2) + exp2f((t1 - mn) * K2)
             + exp2f((t2 - mn) * K2) + exp2f((t3 - mn) * K2)
             + exp2f((t4 - mn) * K2) + exp2f((t5 - mn) * K2)
             + exp2f((t6 - mn) * K2) + exp2f((t7 - mn) * K2);
    s = s * exp2f((m - mn) * K2) + a;
    m = mn;
}

static __device__ __forceinline__ void red_ms(float& m, float& s) {
    #pragma unroll
    for (int o = 32; o > 0; o >>= 1) {
        float mo = __shfl_xor(m, o, 64);
        float so = __shfl_xor(s, o, 64);
        float mn = fmaxf(m, mo);
        s = s * exp2f((m - mn) * K2) + so * exp2f((mo - mn) * K2);
        m = mn;
    }
}

// ---------------- prep kernels ----------------

__global__ void k_init(float* g, float* scalars, int M) {
    int i = blockIdx.x * blockDim.x + threadIdx.x;
    if (i < M) g[i] = 0.f;
    if (i < 8) scalars[i] = 0.f;
}

// one block (64 threads) per row: f32 -> bf16 copy + squared norm (norm from f32, exact)
__global__ void k_convnorm(const float* __restrict__ X, unsigned short* __restrict__ Xb,
                           float* __restrict__ xx, int D) {
    int row = blockIdx.x, lane = threadIdx.x;
    const float* p = X + (size_t)row * D;
    unsigned short* q = Xb + (size_t)row * D;
    float sq = 0.f;
    for (int base = lane * 8; base < D; base += 512) {
        vf4 a = *(const vf4*)(p + base);
        vf4 b = *(const vf4*)(p + base + 4);
        vu8 o;
        #pragma unroll
        for (int e = 0; e < 4; ++e) {
            o[e]     = f2bf(a[e]);
            o[4 + e] = f2bf(b[e]);
            sq += a[e] * a[e] + b[e] * b[e];
        }
        *(vu8*)(q + base) = o;
    }
    sq = wave_red_sum(sq);
    if (lane == 0) xx[row] = sq;
}

__global__ void k_sumtgt(const float* __restrict__ t, float* scalars, int M) {
    __shared__ float red[4];
    float s = 0.f;
    for (int i = threadIdx.x; i < M; i += 256) s += t[i];
    s = wave_red_sum(s);
    if ((threadIdx.x & 63) == 0) red[threadIdx.x >> 6] = s;
    __syncthreads();
    if (threadIdx.x == 0) scalars[3] = logf(red[0] + red[1] + red[2] + red[3]);
}

__global__ void k_rlb(const float* __restrict__ tgt, const float* __restrict__ scalars,
                      float* __restrict__ rlb, int M) {
    int j = blockIdx.x * 256 + threadIdx.x;
    if (j < M) rlb[j] = REGP * (logf(tgt[j]) - scalars[3]);
}

// ---------------- cost matrix: C = sqrt(max(xx+yy-2 X.Y^T, 1e-12)), fp16 C and C^T ----------------

__global__ __launch_bounds__(256, 2)
void k_gemm(const unsigned short* __restrict__ Xb, const unsigned short* __restrict__ Yb,
            const float* __restrict__ xx, const float* __restrict__ yy,
            unsigned short* __restrict__ C, unsigned short* __restrict__ CT,
            int N, int M, int D) {
    int m0 = blockIdx.y * 128, n0 = blockIdx.x * 128;
    int wave = threadIdx.x >> 6, lane = threadIdx.x & 63;
    int lr = lane & 15, lk = (lane >> 4) * 8;
    const unsigned short* ax = Xb + (size_t)(m0 + wave * 32 + lr) * D + lk;
    const unsigned short* bx = Yb + (size_t)(n0 + lr) * D + lk;
    vf4 acc[2][8];
    #pragma unroll
    for (int r = 0; r < 2; ++r)
        #pragma unroll
        for (int c = 0; c < 8; ++c) acc[r][c] = (vf4){0.f, 0.f, 0.f, 0.f};

    for (int k = 0; k < D; k += 32) {
        vbf8 a0 = *(const vbf8*)(ax + k);
        vbf8 a1 = *(const vbf8*)(ax + 16 * D + k);
        #pragma unroll
        for (int c = 0; c < 8; ++c) {
            vbf8 b = *(const vbf8*)(bx + (size_t)c * 16 * D + k);
            acc[0][c] = __builtin_amdgcn_mfma_f32_16x16x32_bf16(a0, b, acc[0][c], 0, 0, 0);
            acc[1][c] = __builtin_amdgcn_mfma_f32_16x16x32_bf16(a1, b, acc[1][c], 0, 0, 0);
        }
    }
    // C/D layout: col = lane&15, row = (lane>>4)*4 + q   [m89-verified]
    int rbase = m0 + wave * 32 + (lane >> 4) * 4;
    #pragma unroll
    for (int r = 0; r < 2; ++r) {
        #pragma unroll
        for (int q = 0; q < 4; ++q) {
            int i = rbase + r * 16 + q;
            float xi = xx[i];
            #pragma unroll
            for (int c = 0; c < 8; ++c) {
                int j = n0 + c * 16 + lr;
                float sq = xi + yy[j] - 2.f * acc[r][c][q];
                _Float16 h = (_Float16)sqrtf(fmaxf(sq, 1e-12f));
                unsigned short hb = *(unsigned short*)&h;
                C[(size_t)i * M + j] = hb;
                CT[(size_t)j * N + i] = hb;
            }
        }
    }
}

// ---------------- sinkhorn pass: vout[r] = off_r - reg*logsumexp((vin - Cmat[r,:])/reg) ----------------
// 2 rows per wave, 4 waves/block, 2-chunk unroll (width multiple of 1024)

__global__ __launch_bounds__(256)
void k_pass(const unsigned short* __restrict__ Cmat, const float* __restrict__ vin,
            float* __restrict__ vout, const float* __restrict__ rlb, float rla, int width) {
    int row0 = (blockIdx.x * 4 + (threadIdx.x >> 6)) * 2;
    int lane = threadIdx.x & 63;
    const unsigned short* cp = Cmat + (size_t)row0 * width;
    float mA = -1e30f, sA = 0.f, mB = -1e30f, sB = 0.f;
    for (int base = lane * 8; base < width; base += 1024) {
        vf4 ga0 = *(const vf4*)(vin + base);
        vf4 gb0 = *(const vf4*)(vin + base + 4);
        vf4 ga1 = *(const vf4*)(vin + base + 512);
        vf4 gb1 = *(const vf4*)(vin + base + 516);
        vh8 hA0 = *(const vh8*)(cp + base);
        vh8 hA1 = *(const vh8*)(cp + base + 512);
        vh8 hB0 = *(const vh8*)(cp + width + base);
        vh8 hB1 = *(const vh8*)(cp + width + base + 512);
        upd(hA0, ga0, gb0, mA, sA);
        upd(hA1, ga1, gb1, mA, sA);
        upd(hB0, ga0, gb0, mB, sB);
        upd(hB1, ga1, gb1, mB, sB);
    }
    red_ms(mA, sA);
    red_ms(mB, sB);
    if (lane == 0) {
        vout[row0]     = (rlb ? rlb[row0]     : rla) - mA - REGP * logf(sA);
        vout[row0 + 1] = (rlb ? rlb[row0 + 1] : rla) - mB - REGP * logf(sB);
    }
}

// ---------------- epilogue: sum P*C ----------------

__global__ __launch_bounds__(256)
void k_ot(const unsigned short* __restrict__ C, const float* __restrict__ f,
          const float* __restrict__ g, float* __restrict__ scalars, int M) {
    int row = blockIdx.x * 4 + (threadIdx.x >> 6);
    int lane = threadIdx.x & 63;
    const unsigned short* cp = C + (size_t)row * M;
    float fi = f[row];
    float acc = 0.f;
    for (int base = lane * 8; base < M; base += 512) {
        vh8 hv = *(const vh8*)(cp + base);
        vf4 g0 = *(const vf4*)(g + base);
        vf4 g1 = *(const vf4*)(g + base + 4);
        #pragma unroll
        for (int e = 0; e < 4; ++e) {
            float c0 = (float)hv[e], c1 = (float)hv[4 + e];
            acc += exp2f((fi + g0[e] - c0) * K2) * c0;
            acc += exp2f((fi + g1[e] - c1) * K2) * c1;
        }
    }
    acc = wave_red_sum(acc);
    if (lane == 0) atomicAdd(&scalars[0], acc);
}

__global__ void k_dist(const float* __restrict__ X, const float* __restrict__ Y,
                       const int* __restrict__ aligned, float* __restrict__ scalars, int D) {
    int i = blockIdx.x, lane = threadIdx.x;
    int a = aligned[i];
    if (a == -1) return;
    const float* xp = X + (size_t)i * D;
    const float* yp = Y + (size_t)a * D;
    float sq = 0.f;
    for (int base = lane * 8; base < D; base += 512) {
        vf4 x0 = *(const vf4*)(xp + base), x1 = *(const vf4*)(xp + base + 4);
        vf4 y0 = *(const vf4*)(yp + base), y1 = *(const vf4*)(yp + base + 4);
        #pragma unroll
        for (int e = 0; e < 4; ++e) {
            float d0 = x0[e] - y0[e], d1 = x1[e] - y1[e];
            sq += d0 * d0 + d1 * d1;
        }
    }
    sq = wave_red_sum(sq);
    if (lane == 0) { atomicAdd(&scalars[1], sq); atomicAdd(&scalars[2], 1.0f); }
}

__global__ void k_final(float* out, const float* __restrict__ scalars, int D) {
    float cnt = scalars[2];
    float dist = cnt > 0.f ? scalars[1] / (cnt * (float)D) : 0.f;
    out[0] = scalars[0] + dist;
}

// ---------------- host ----------------

extern "C" void kernel_launch(void* const* d_in, const int* in_sizes, int n_in,
                              void* d_out, int out_size, void* d_ws, size_t ws_size,
                              hipStream_t stream) {
    const float* X = (const float*)d_in[0];
    const float* Y = (const float*)d_in[1];
    const int* aligned = (const int*)d_in[2];
    const float* tgt = (const float*)d_in[3];
    int N = in_sizes[2];              // 4096
    int M = in_sizes[3];              // 8192
    int D = in_sizes[0] / N;          // 512
    float* out = (float*)d_out;

    char* w = (char*)d_ws;
    size_t off = 0;
    auto alloc = [&](size_t bytes) -> void* {
        void* p = w + off;
        off += (bytes + 255) & ~(size_t)255;
        return p;
    };
    unsigned short* Xb = (unsigned short*)alloc((size_t)N * D * 2);
    unsigned short* Yb = (unsigned short*)alloc((size_t)M * D * 2);
    unsigned short* C  = (unsigned short*)alloc((size_t)N * M * 2);
    unsigned short* CT = (unsigned short*)alloc((size_t)N * M * 2);
    float* xx  = (float*)alloc((size_t)N * 4);
    float* yy  = (float*)alloc((size_t)M * 4);
    float* f   = (float*)alloc((size_t)N * 4);
    float* g   = (float*)alloc((size_t)M * 4);
    float* rlb = (float*)alloc((size_t)M * 4);
    float* scalars = (float*)alloc(64);
    if (off > ws_size) return;  // workspace too small — cannot proceed

    float rla = -REGP * logf((float)N);

    k_init<<<dim3((M + 255) / 256), 256, 0, stream>>>(g, scalars, M);
    k_convnorm<<<dim3(N), 64, 0, stream>>>(X, Xb, xx, D);
    k_convnorm<<<dim3(M), 64, 0, stream>>>(Y, Yb, yy, D);
    k_sumtgt<<<1, 256, 0, stream>>>(tgt, scalars, M);
    k_rlb<<<dim3((M + 255) / 256), 256, 0, stream>>>(tgt, scalars, rlb, M);
    k_gemm<<<dim3(M / 128, N / 128), 256, 0, stream>>>(Xb, Yb, xx, yy, C, CT, N, M, D);

    for (int it = 0; it < NIT; ++it) {
        k_pass<<<dim3(N / 8), 256, 0, stream>>>(C,  g, f, nullptr, rla, M);
        k_pass<<<dim3(M / 8), 256, 0, stream>>>(CT, f, g, rlb,     0.f, N);
    }

    k_ot<<<dim3(N / 4), 256, 0, stream>>>(C, f, g, scalars, M);
    k_dist<<<dim3(N), 64, 0, stream>>>(X, Y, aligned, scalars, D);
    k_final<<<1, 1, 0, stream>>>(out, scalars, D);
}

// Round 2
// 5743.563 us; speedup vs baseline: 1.3176x; 1.3176x over previous
//
#include <hip/hip_runtime.h>
#include <cmath>

#define REGP 0.1f
#define NIT 200
#define K2 14.4269504089f        // log2(e)/reg
#define CREF 28.5f               // centering constant for f
#define CLO  23.5f               // u8 quantization lower bound
#define QSV  (17.0f/255.0f)      // quant step
#define QIV  15.0f               // 1/QSV
#define S2V  (QSV*K2)

typedef float  vf4  __attribute__((ext_vector_type(4)));
typedef short  vbf8 __attribute__((ext_vector_type(8)));
typedef unsigned short vu8 __attribute__((ext_vector_type(8)));

#if defined(__has_builtin) && __has_builtin(__builtin_amdgcn_exp2f)
#define EXP2F(x) __builtin_amdgcn_exp2f(x)
#else
#define EXP2F(x) exp2f(x)
#endif

static __device__ __forceinline__ unsigned short f2bf(float x) {
    unsigned int u = __float_as_uint(x);
    return (unsigned short)((u + 0x7FFFu + ((u >> 16) & 1u)) >> 16);
}

static __device__ __forceinline__ float wave_red_sum(float v) {
    #pragma unroll
    for (int o = 32; o > 0; o >>= 1) v += __shfl_xor(v, o, 64);
    return v;
}

// 16 u8 cost values vs 16 gk values; 4 independent accumulators (sacc = vf4)
static __device__ __forceinline__ void acc16(uint4 c, const vf4* gv, vf4& sacc) {
    #pragma unroll
    for (int d = 0; d < 4; ++d) {
        unsigned x = d == 0 ? c.x : d == 1 ? c.y : d == 2 ? c.z : c.w;
        vf4 g = gv[d];
        sacc[0] += EXP2F(fmaf((float)(x & 0xffu),         -S2V, g[0]));
        sacc[1] += EXP2F(fmaf((float)((x >> 8) & 0xffu),  -S2V, g[1]));
        sacc[2] += EXP2F(fmaf((float)((x >> 16) & 0xffu), -S2V, g[2]));
        sacc[3] += EXP2F(fmaf((float)(x >> 24),           -S2V, g[3]));
    }
}

// ---------------- prep kernels ----------------

__global__ void k_init(float* gk, float* scalars, int M) {
    int i = blockIdx.x * blockDim.x + threadIdx.x;
    if (i < M) gk[i] = 5.0f * K2;        // g=0: gk=(0-0+5)*K2
    if (i < 8) scalars[i] = 0.f;
}

__global__ void k_convnorm(const float* __restrict__ X, unsigned short* __restrict__ Xb,
                           float* __restrict__ xx, int D) {
    int row = blockIdx.x, lane = threadIdx.x;
    const float* p = X + (size_t)row * D;
    unsigned short* q = Xb + (size_t)row * D;
    float sq = 0.f;
    for (int base = lane * 8; base < D; base += 512) {
        vf4 a = *(const vf4*)(p + base);
        vf4 b = *(const vf4*)(p + base + 4);
        vu8 o;
        #pragma unroll
        for (int e = 0; e < 4; ++e) {
            o[e]     = f2bf(a[e]);
            o[4 + e] = f2bf(b[e]);
            sq += a[e] * a[e] + b[e] * b[e];
        }
        *(vu8*)(q + base) = o;
    }
    sq = wave_red_sum(sq);
    if (lane == 0) xx[row] = sq;
}

__global__ void k_sumtgt(const float* __restrict__ t, float* scalars, int M) {
    __shared__ float red[4];
    float s = 0.f;
    for (int i = threadIdx.x; i < M; i += 256) s += t[i];
    s = wave_red_sum(s);
    if ((threadIdx.x & 63) == 0) red[threadIdx.x >> 6] = s;
    __syncthreads();
    if (threadIdx.x == 0) scalars[3] = logf(red[0] + red[1] + red[2] + red[3]);
}

__global__ void k_rlb(const float* __restrict__ tgt, const float* __restrict__ scalars,
                      float* __restrict__ rlb, int M) {
    int j = blockIdx.x * 256 + threadIdx.x;
    if (j < M) rlb[j] = REGP * (logf(tgt[j]) - scalars[3]);
}

// ---------------- cost matrix: OUT[i][j] = quant_u8(sqrt(an[i]+bn[j]-2 A_i.B_j)) ----------------
// run twice (A/B swapped) to produce C and CT with identical quantized values

__global__ __launch_bounds__(256, 2)
void k_gemm(const unsigned short* __restrict__ A, const unsigned short* __restrict__ B,
            const float* __restrict__ an, const float* __restrict__ bn,
            unsigned char* __restrict__ OUT, int ldo, int D) {
    int m0 = blockIdx.y * 128, n0 = blockIdx.x * 128;
    int wave = threadIdx.x >> 6, lane = threadIdx.x & 63;
    int lr = lane & 15, lk = (lane >> 4) * 8;
    const unsigned short* ax = A + (size_t)(m0 + wave * 32 + lr) * D + lk;
    const unsigned short* bx = B + (size_t)(n0 + lr) * D + lk;
    vf4 acc[2][8];
    #pragma unroll
    for (int r = 0; r < 2; ++r)
        #pragma unroll
        for (int c = 0; c < 8; ++c) acc[r][c] = (vf4){0.f, 0.f, 0.f, 0.f};

    for (int k = 0; k < D; k += 32) {
        vbf8 a0 = *(const vbf8*)(ax + k);
        vbf8 a1 = *(const vbf8*)(ax + 16 * D + k);
        #pragma unroll
        for (int c = 0; c < 8; ++c) {
            vbf8 b = *(const vbf8*)(bx + (size_t)c * 16 * D + k);
            acc[0][c] = __builtin_amdgcn_mfma_f32_16x16x32_bf16(a0, b, acc[0][c], 0, 0, 0);
            acc[1][c] = __builtin_amdgcn_mfma_f32_16x16x32_bf16(a1, b, acc[1][c], 0, 0, 0);
        }
    }
    int rbase = m0 + wave * 32 + (lane >> 4) * 4;
    #pragma unroll
    for (int r = 0; r < 2; ++r) {
        #pragma unroll
        for (int q = 0; q < 4; ++q) {
            int i = rbase + r * 16 + q;
            float xi = an[i];
            #pragma unroll
            for (int c = 0; c < 8; ++c) {
                int j = n0 + c * 16 + lr;
                float sq = xi + bn[j] - 2.f * acc[r][c][q];
                float cv = sqrtf(fmaxf(sq, 1e-12f));
                float qv = fminf(fmaxf((cv - CLO) * QIV, 0.f), 255.f);
                OUT[(size_t)i * ldo + j] = (unsigned char)(qv + 0.5f);
            }
        }
    }
}

// ---------------- sinkhorn pass ----------------
// vout[r] = off_r + outbase - log2(sum_j exp2(gk_j - u8[r][j]*S2)) / K2
// block: 4 rows; wave w: rows (w>>1)*2 + {0,1}, width-half h=w&1; lane: 32 cols/chunk

template<int CHUNKS>
__global__ __launch_bounds__(256)
void k_pass(const unsigned char* __restrict__ Cm, const float* __restrict__ vk,
            float* __restrict__ vout, float* __restrict__ vkout,
            const float* __restrict__ rlb, float rla,
            float outbase, float outkoff, int width) {
    __shared__ float sred[8];
    int tid = threadIdx.x;
    int w = tid >> 6, lane = tid & 63;
    int rp = w >> 1, h = w & 1;
    int r0 = blockIdx.x * 4 + rp * 2;
    int half = width >> 1;
    const unsigned char* cp = Cm + (size_t)r0 * width + h * half + lane * 32;
    const float* gp = vk + h * half + lane * 32;
    vf4 sA = (vf4){0.f,0.f,0.f,0.f}, sB = (vf4){0.f,0.f,0.f,0.f};
    #pragma unroll
    for (int ch = 0; ch < CHUNKS; ++ch) {
        const int o = ch * 2048;
        uint4 a0 = *(const uint4*)(cp + o);
        uint4 a1 = *(const uint4*)(cp + o + 16);
        uint4 b0 = *(const uint4*)(cp + o + width);
        uint4 b1 = *(const uint4*)(cp + o + width + 16);
        vf4 gv[8];
        #pragma unroll
        for (int q = 0; q < 8; ++q) gv[q] = *(const vf4*)(gp + o + q * 4);
        acc16(a0, &gv[0], sA);
        acc16(a1, &gv[4], sA);
        acc16(b0, &gv[0], sB);
        acc16(b1, &gv[4], sB);
    }
    float s0 = wave_red_sum(sA[0] + sA[1] + sA[2] + sA[3]);
    float s1 = wave_red_sum(sB[0] + sB[1] + sB[2] + sB[3]);
    if (lane == 0) {
        sred[(rp * 2 + 0) * 2 + h] = s0;
        sred[(rp * 2 + 1) * 2 + h] = s1;
    }
    __syncthreads();
    if (tid < 4) {
        float s = sred[tid * 2] + sred[tid * 2 + 1];
        int row = blockIdx.x * 4 + tid;
        float off = rlb ? rlb[row] : rla;
        float val = off + outbase - log2f(s) * (1.0f / K2);
        vout[row] = val;
        vkout[row] = (val + outkoff) * K2;
    }
}

// ---------------- epilogue: sum P*C' ----------------

__global__ __launch_bounds__(256)
void k_ot(const unsigned char* __restrict__ C, const float* __restrict__ f,
          const float* __restrict__ gk, float* __restrict__ scalars, int M) {
    int row = blockIdx.x * 4 + (threadIdx.x >> 6);
    int lane = threadIdx.x & 63;
    const unsigned char* cp = C + (size_t)row * M;
    float fk2 = (f[row] - CREF) * K2;
    float acc = 0.f;
    for (int base = lane * 16; base < M; base += 1024) {
        uint4 cw = *(const uint4*)(cp + base);
        #pragma unroll
        for (int d = 0; d < 4; ++d) {
            unsigned x = d == 0 ? cw.x : d == 1 ? cw.y : d == 2 ? cw.z : cw.w;
            vf4 g = *(const vf4*)(gk + base + d * 4);
            #pragma unroll
            for (int e = 0; e < 4; ++e) {
                float uf = (float)((x >> (8 * e)) & 0xffu);
                float t = fmaf(uf, -S2V, fk2 + g[e]);
                float cval = fmaf(uf, QSV, CLO);
                acc = fmaf(EXP2F(t), cval, acc);
            }
        }
    }
    acc = wave_red_sum(acc);
    if (lane == 0) atomicAdd(&scalars[0], acc);
}

__global__ void k_dist(const float* __restrict__ X, const float* __restrict__ Y,
                       const int* __restrict__ aligned, float* __restrict__ scalars, int D) {
    int i = blockIdx.x, lane = threadIdx.x;
    int a = aligned[i];
    if (a == -1) return;
    const float* xp = X + (size_t)i * D;
    const float* yp = Y + (size_t)a * D;
    float sq = 0.f;
    for (int base = lane * 8; base < D; base += 512) {
        vf4 x0 = *(const vf4*)(xp + base), x1 = *(const vf4*)(xp + base + 4);
        vf4 y0 = *(const vf4*)(yp + base), y1 = *(const vf4*)(yp + base + 4);
        #pragma unroll
        for (int e = 0; e < 4; ++e) {
            float d0 = x0[e] - y0[e], d1 = x1[e] - y1[e];
            sq += d0 * d0 + d1 * d1;
        }
    }
    sq = wave_red_sum(sq);
    if (lane == 0) { atomicAdd(&scalars[1], sq); atomicAdd(&scalars[2], 1.0f); }
}

__global__ void k_final(float* out, const float* __restrict__ scalars, int D) {
    float cnt = scalars[2];
    float dist = cnt > 0.f ? scalars[1] / (cnt * (float)D) : 0.f;
    out[0] = scalars[0] + dist;
}

// ---------------- host ----------------

extern "C" void kernel_launch(void* const* d_in, const int* in_sizes, int n_in,
                              void* d_out, int out_size, void* d_ws, size_t ws_size,
                              hipStream_t stream) {
    const float* X = (const float*)d_in[0];
    const float* Y = (const float*)d_in[1];
    const int* aligned = (const int*)d_in[2];
    const float* tgt = (const float*)d_in[3];
    int N = in_sizes[2];              // 4096
    int M = in_sizes[3];              // 8192
    int D = in_sizes[0] / N;          // 512
    float* out = (float*)d_out;

    char* w = (char*)d_ws;
    size_t off = 0;
    auto alloc = [&](size_t bytes) -> void* {
        void* p = w + off;
        off += (bytes + 255) & ~(size_t)255;
        return p;
    };
    unsigned short* Xb = (unsigned short*)alloc((size_t)N * D * 2);
    unsigned short* Yb = (unsigned short*)alloc((size_t)M * D * 2);
    unsigned char* C  = (unsigned char*)alloc((size_t)N * M);
    unsigned char* CT = (unsigned char*)alloc((size_t)N * M);
    float* xx  = (float*)alloc((size_t)N * 4);
    float* yy  = (float*)alloc((size_t)M * 4);
    float* f   = (float*)alloc((size_t)N * 4);
    float* g   = (float*)alloc((size_t)M * 4);
    float* fk  = (float*)alloc((size_t)N * 4);
    float* gk  = (float*)alloc((size_t)M * 4);
    float* rlb = (float*)alloc((size_t)M * 4);
    float* scalars = (float*)alloc(64);
    if (off > ws_size) return;

    float rla = -REGP * logf((float)N);

    k_init<<<dim3((M + 255) / 256), 256, 0, stream>>>(gk, scalars, M);
    k_convnorm<<<dim3(N), 64, 0, stream>>>(X, Xb, xx, D);
    k_convnorm<<<dim3(M), 64, 0, stream>>>(Y, Yb, yy, D);
    k_sumtgt<<<1, 256, 0, stream>>>(tgt, scalars, M);
    k_rlb<<<dim3((M + 255) / 256), 256, 0, stream>>>(tgt, scalars, rlb, M);
    k_gemm<<<dim3(M / 128, N / 128), 256, 0, stream>>>(Xb, Yb, xx, yy, C,  M, D);
    k_gemm<<<dim3(N / 128, M / 128), 256, 0, stream>>>(Yb, Xb, yy, xx, CT, N, D);

    for (int it = 0; it < NIT; ++it) {
        // f-pass: width M, half=4096 -> 2 chunks
        k_pass<2><<<dim3(N / 4), 256, 0, stream>>>(C,  gk, f, fk, nullptr, rla, CREF, -CLO, M);
        // g-pass: width N, half=2048 -> 1 chunk
        k_pass<1><<<dim3(M / 4), 256, 0, stream>>>(CT, fk, g, gk, rlb, 0.f, 0.f, CREF - CLO, N);
    }

    k_ot<<<dim3(N / 4), 256, 0, stream>>>(C, f, gk, scalars, M);
    k_dist<<<dim3(N), 64, 0, stream>>>(X, Y, aligned, scalars, D);
    k_final<<<1, 1, 0, stream>>>(out, scalars, D);
}